// Round 1
// baseline (1221.829 us; speedup 1.0000x reference)
//
#include <hip/hip_runtime.h>
#include <math.h>

#define BB 2
#define SS 2048
#define DD 1024
#define HH 16
#define HDD 64

// ============================================================
// Projection GEMM: OUT = (X @ W + bias) * post
//   X: (M=BB*SS, DD) row-major; W: (DD, DD) row-major; bias: (DD)
//   PERM=true : out[((b*HH+h)*SS+s)*HDD+hd]   (B,H,S,HD layout)
//   PERM=false: out[r*DD+c]                   (flat row-major)
// Tile: BM=128 x BN=64, BK=16, 256 threads, 8x4 per thread.
// ============================================================
template<bool PERM>
__global__ __launch_bounds__(256)
void proj_gemm(const float* __restrict__ X, const float* __restrict__ W,
               const float* __restrict__ bias, float* __restrict__ out,
               float post)
{
    constexpr int BM = 128, BN = 64, BK = 16;
    __shared__ float As[BK][BM + 4];   // [k][m]  (transposed A tile)
    __shared__ float Bs[BK][BN + 4];   // [k][n]

    const int t  = threadIdx.x;
    const int ty = t >> 4;      // 0..15 -> rows ty*8
    const int tx = t & 15;      // 0..15 -> cols tx*4
    const int m0 = blockIdx.y * BM;
    const int n0 = blockIdx.x * BN;

    float acc[8][4];
#pragma unroll
    for (int r = 0; r < 8; ++r)
#pragma unroll
        for (int c = 0; c < 4; ++c) acc[r][c] = 0.f;

    for (int k0 = 0; k0 < DD; k0 += BK) {
        __syncthreads();
        // stage A tile (128x16), transposed into LDS
#pragma unroll
        for (int li = 0; li < 2; ++li) {
            int idx = t + li * 256;          // 0..511 float4 slots
            int row = idx >> 2;              // 0..127
            int c4  = (idx & 3) << 2;        // 0,4,8,12
            const float4 v = *reinterpret_cast<const float4*>(
                &X[(size_t)(m0 + row) * DD + k0 + c4]);
            As[c4 + 0][row] = v.x;
            As[c4 + 1][row] = v.y;
            As[c4 + 2][row] = v.z;
            As[c4 + 3][row] = v.w;
        }
        // stage B tile (16x64)
        {
            int k  = t >> 4;
            int c4 = (t & 15) << 2;
            const float4 v = *reinterpret_cast<const float4*>(
                &W[(size_t)(k0 + k) * DD + n0 + c4]);
            *reinterpret_cast<float4*>(&Bs[k][c4]) = v;
        }
        __syncthreads();
#pragma unroll
        for (int kk = 0; kk < BK; ++kk) {
            float4 a0 = *reinterpret_cast<const float4*>(&As[kk][ty * 8 + 0]);
            float4 a1 = *reinterpret_cast<const float4*>(&As[kk][ty * 8 + 4]);
            float4 b0 = *reinterpret_cast<const float4*>(&Bs[kk][tx * 4]);
            float ar[8] = {a0.x, a0.y, a0.z, a0.w, a1.x, a1.y, a1.z, a1.w};
            float bc[4] = {b0.x, b0.y, b0.z, b0.w};
#pragma unroll
            for (int r = 0; r < 8; ++r)
#pragma unroll
                for (int c = 0; c < 4; ++c)
                    acc[r][c] = fmaf(ar[r], bc[c], acc[r][c]);
        }
    }

    // epilogue
#pragma unroll
    for (int r = 0; r < 8; ++r) {
        int row = m0 + ty * 8 + r;
        int col = n0 + tx * 4;
        float4 v;
        v.x = (acc[r][0] + bias[col + 0]) * post;
        v.y = (acc[r][1] + bias[col + 1]) * post;
        v.z = (acc[r][2] + bias[col + 2]) * post;
        v.w = (acc[r][3] + bias[col + 3]) * post;
        if (PERM) {
            int b = row >> 11;            // row / SS
            int s = row & (SS - 1);
            int h = col >> 6;             // col / HDD
            int hd = col & (HDD - 1);
            *reinterpret_cast<float4*>(
                &out[(((size_t)(b * HH + h)) * SS + s) * HDD + hd]) = v;
        } else {
            *reinterpret_cast<float4*>(&out[(size_t)row * DD + col]) = v;
        }
    }
}

// ============================================================
// Flash attention (fp32): one block = (b, h, 64 q-rows).
// Q pre-scaled by 1/8 in the projection (exact pow2).
// scores[b,h,i,j] = Q.K + rpb[j,i,h]; masked -> -1e9; online softmax.
// LDS: Qt[d][i], U (K^T[d][j] during scores, P^T[j][i] during PV), Vs[k][c].
// ============================================================
__global__ __launch_bounds__(256)
void attn_fwd(const float* __restrict__ Qw, const float* __restrict__ Kw,
              const float* __restrict__ Vw, const int* __restrict__ mask,
              const float* __restrict__ rpb, float* __restrict__ AO)
{
    __shared__ float Qt[HDD][68];   // [d][i]
    __shared__ float U [HDD][68];   // Kt [d][j]  /  Ps [j][i]
    __shared__ float Vs[64][68];    // [kk][c]

    const int t  = threadIdx.x;
    const int ty = t >> 4;          // 0..15 -> rows i = ty*4
    const int tx = t & 15;          // 0..15 -> cols j = tx*4
    const int i0 = blockIdx.x * 64;
    const int h  = blockIdx.y;
    const int b  = blockIdx.z;
    const size_t bh = (size_t)(b * HH + h) * SS;

    // load Q tile (64x64), transposed
#pragma unroll
    for (int li = 0; li < 4; ++li) {
        int idx = t + li * 256;          // 0..1023 float4 slots
        int row = idx >> 4;              // 0..63
        int d0  = (idx & 15) << 2;
        const float4 v = *reinterpret_cast<const float4*>(
            &Qw[(bh + i0 + row) * HDD + d0]);
        Qt[d0 + 0][row] = v.x;
        Qt[d0 + 1][row] = v.y;
        Qt[d0 + 2][row] = v.z;
        Qt[d0 + 3][row] = v.w;
    }

    float acc[4][4];
    float mrow[4], lrow[4];
#pragma unroll
    for (int r = 0; r < 4; ++r) {
        mrow[r] = -INFINITY;
        lrow[r] = 0.f;
#pragma unroll
        for (int c = 0; c < 4; ++c) acc[r][c] = 0.f;
    }

    for (int kt = 0; kt < SS / 64; ++kt) {
        const int j0 = kt * 64;

        // prefetch bias + mask into registers (covers latency under staging)
        float bv[4][4];
        int   mk[4][4];
#pragma unroll
        for (int c = 0; c < 4; ++c) {
            int j = j0 + tx * 4 + c;
#pragma unroll
            for (int r = 0; r < 4; ++r) {
                int i = i0 + ty * 4 + r;
                bv[r][c] = rpb[((size_t)j * SS + i) * HH + h];
            }
        }
#pragma unroll
        for (int r = 0; r < 4; ++r) {
            int i = i0 + ty * 4 + r;
            const int4 m4 = *reinterpret_cast<const int4*>(
                &mask[((size_t)b * SS + i) * SS + j0 + tx * 4]);
            mk[r][0] = m4.x; mk[r][1] = m4.y; mk[r][2] = m4.z; mk[r][3] = m4.w;
        }

        __syncthreads();   // previous PV done -> safe to overwrite U, Vs
        // stage K (transposed) and V (natural)
#pragma unroll
        for (int li = 0; li < 4; ++li) {
            int idx = t + li * 256;
            int row = idx >> 4;
            int d0  = (idx & 15) << 2;
            const float4 kv = *reinterpret_cast<const float4*>(
                &Kw[(bh + j0 + row) * HDD + d0]);
            U[d0 + 0][row] = kv.x;
            U[d0 + 1][row] = kv.y;
            U[d0 + 2][row] = kv.z;
            U[d0 + 3][row] = kv.w;
            const float4 vv = *reinterpret_cast<const float4*>(
                &Vw[(bh + j0 + row) * HDD + d0]);
            *reinterpret_cast<float4*>(&Vs[row][d0]) = vv;
        }
        __syncthreads();

        // scores: 4x4 per thread, dot over d=0..63
        float sa[4][4];
#pragma unroll
        for (int r = 0; r < 4; ++r)
#pragma unroll
            for (int c = 0; c < 4; ++c) sa[r][c] = 0.f;
#pragma unroll 4
        for (int d = 0; d < HDD; ++d) {
            float4 qa = *reinterpret_cast<const float4*>(&Qt[d][ty * 4]);
            float4 kb = *reinterpret_cast<const float4*>(&U[d][tx * 4]);
            float qr[4] = {qa.x, qa.y, qa.z, qa.w};
            float kc[4] = {kb.x, kb.y, kb.z, kb.w};
#pragma unroll
            for (int r = 0; r < 4; ++r)
#pragma unroll
                for (int c = 0; c < 4; ++c)
                    sa[r][c] = fmaf(qr[r], kc[c], sa[r][c]);
        }
        __syncthreads();   // Kt dead -> U reusable for P^T

        // bias + mask
#pragma unroll
        for (int r = 0; r < 4; ++r)
#pragma unroll
            for (int c = 0; c < 4; ++c) {
                float s = sa[r][c] + bv[r][c];
                sa[r][c] = (mk[r][c] == 0) ? -1e9f : s;
            }

        // online softmax (row groups = 16 consecutive lanes, shfl_xor reduce)
#pragma unroll
        for (int r = 0; r < 4; ++r) {
            float rm = fmaxf(fmaxf(sa[r][0], sa[r][1]), fmaxf(sa[r][2], sa[r][3]));
            rm = fmaxf(rm, __shfl_xor(rm, 1));
            rm = fmaxf(rm, __shfl_xor(rm, 2));
            rm = fmaxf(rm, __shfl_xor(rm, 4));
            rm = fmaxf(rm, __shfl_xor(rm, 8));
            float mn = fmaxf(mrow[r], rm);
            float sc = __expf(mrow[r] - mn);   // exp(-inf)=0 on first tile
            mrow[r] = mn;
            float ps = 0.f;
#pragma unroll
            for (int c = 0; c < 4; ++c) {
                float p = __expf(sa[r][c] - mn);
                sa[r][c] = p;
                ps += p;
            }
            ps += __shfl_xor(ps, 1);
            ps += __shfl_xor(ps, 2);
            ps += __shfl_xor(ps, 4);
            ps += __shfl_xor(ps, 8);
            lrow[r] = lrow[r] * sc + ps;
#pragma unroll
            for (int c = 0; c < 4; ++c) acc[r][c] *= sc;
        }

        // write P^T into U: U[j][i]
#pragma unroll
        for (int c = 0; c < 4; ++c) {
            float4 pv;
            pv.x = sa[0][c]; pv.y = sa[1][c]; pv.z = sa[2][c]; pv.w = sa[3][c];
            *reinterpret_cast<float4*>(&U[tx * 4 + c][ty * 4]) = pv;
        }
        __syncthreads();

        // PV: acc[i][c] += sum_kk P[i][kk] * V[kk][c]
#pragma unroll 4
        for (int kk = 0; kk < 64; ++kk) {
            float4 pa = *reinterpret_cast<const float4*>(&U[kk][ty * 4]);
            float4 vb = *reinterpret_cast<const float4*>(&Vs[kk][tx * 4]);
            float pr[4] = {pa.x, pa.y, pa.z, pa.w};
            float vc[4] = {vb.x, vb.y, vb.z, vb.w};
#pragma unroll
            for (int r = 0; r < 4; ++r)
#pragma unroll
                for (int c = 0; c < 4; ++c)
                    acc[r][c] = fmaf(pr[r], vc[c], acc[r][c]);
        }
    }

    // epilogue: normalize and write (B,S,D)
#pragma unroll
    for (int r = 0; r < 4; ++r) {
        float inv = 1.0f / lrow[r];
        float4 o;
        o.x = acc[r][0] * inv;
        o.y = acc[r][1] * inv;
        o.z = acc[r][2] * inv;
        o.w = acc[r][3] * inv;
        int i = i0 + ty * 4 + r;
        *reinterpret_cast<float4*>(
            &AO[((size_t)b * SS + i) * DD + h * HDD + tx * 4]) = o;
    }
}

extern "C" void kernel_launch(void* const* d_in, const int* in_sizes, int n_in,
                              void* d_out, int out_size, void* d_ws, size_t ws_size,
                              hipStream_t stream)
{
    (void)in_sizes; (void)n_in; (void)out_size; (void)ws_size;

    const float* query = (const float*)d_in[0];
    const float* key   = (const float*)d_in[1];
    const float* value = (const float*)d_in[2];
    const int*   mask  = (const int*)d_in[3];
    const float* rpb   = (const float*)d_in[4];
    const float* Wq = (const float*)d_in[5];  const float* bq = (const float*)d_in[6];
    const float* Wk = (const float*)d_in[7];  const float* bk = (const float*)d_in[8];
    const float* Wv = (const float*)d_in[9];  const float* bv = (const float*)d_in[10];
    const float* Wo = (const float*)d_in[11]; const float* bo = (const float*)d_in[12];
    float* out = (float*)d_out;

    const size_t per = (size_t)BB * HH * SS * HDD;   // 4M floats
    float* Qw = (float*)d_ws;
    float* Kw = Qw + per;
    float* Vw = Kw + per;
    float* AO = Vw + per;

    dim3 gp(DD / 64, (BB * SS) / 128);
    // Q pre-scaled by 1/sqrt(HD)=0.125 (exact pow2) including bias
    proj_gemm<true><<<gp, 256, 0, stream>>>(query, Wq, bq, Qw, 0.125f);
    proj_gemm<true><<<gp, 256, 0, stream>>>(key,   Wk, bk, Kw, 1.0f);
    proj_gemm<true><<<gp, 256, 0, stream>>>(value, Wv, bv, Vw, 1.0f);

    attn_fwd<<<dim3(SS / 64, HH, BB), 256, 0, stream>>>(Qw, Kw, Vw, mask, rpb, AO);

    proj_gemm<false><<<gp, 256, 0, stream>>>(AO, Wo, bo, out, 1.0f);
}

// Round 2
// 731.488 us; speedup vs baseline: 1.6703x; 1.6703x over previous
//
#include <hip/hip_runtime.h>
#include <math.h>

#define SS 2048
#define DD 1024
#define HH 16

typedef _Float16 f16;
typedef _Float16 half8 __attribute__((ext_vector_type(8)));
typedef float f32x4 __attribute__((ext_vector_type(4)));

__device__ __forceinline__ void gload16(const void* g, void* lds) {
    __builtin_amdgcn_global_load_lds(
        (const __attribute__((address_space(1))) unsigned int*)g,
        (__attribute__((address_space(3))) unsigned int*)lds, 16, 0, 0);
}

// ============================================================
// prep 1: f32 -> f16 elementwise for query/key/value
// ============================================================
__global__ __launch_bounds__(256)
void cvt_x(const float* __restrict__ q, const float* __restrict__ k,
           const float* __restrict__ v, f16* __restrict__ oq,
           f16* __restrict__ ok, f16* __restrict__ ov)
{
    const int z = blockIdx.z;
    const float* src = z == 0 ? q : z == 1 ? k : v;
    f16* dst = z == 0 ? oq : z == 1 ? ok : ov;
    size_t i = ((size_t)blockIdx.x * 256 + threadIdx.x) * 8;
    float4 v0 = *reinterpret_cast<const float4*>(src + i);
    float4 v1 = *reinterpret_cast<const float4*>(src + i + 4);
    half8 h;
    h[0] = (f16)v0.x; h[1] = (f16)v0.y; h[2] = (f16)v0.z; h[3] = (f16)v0.w;
    h[4] = (f16)v1.x; h[5] = (f16)v1.y; h[6] = (f16)v1.z; h[7] = (f16)v1.w;
    *reinterpret_cast<half8*>(dst + i) = h;
}

// ============================================================
// prep 2: W (k,n) f32 -> WT (n,k) f16, 64x64 tiles through LDS
// ============================================================
__global__ __launch_bounds__(256)
void cvt_wT(const float* __restrict__ wq, const float* __restrict__ wk,
            const float* __restrict__ wv, const float* __restrict__ wo,
            f16* __restrict__ oq, f16* __restrict__ ok,
            f16* __restrict__ ov, f16* __restrict__ oo)
{
    __shared__ float Lt[64][65];
    const int z = blockIdx.z;
    const float* W = z == 0 ? wq : z == 1 ? wk : z == 2 ? wv : wo;
    f16* WT = z == 0 ? oq : z == 1 ? ok : z == 2 ? ov : oo;
    const int n0 = blockIdx.x * 64, k0 = blockIdx.y * 64;
    const int t = threadIdx.x;
    {
        int row = t >> 2;               // k-local
        int c0  = (t & 3) * 16;         // n-local
#pragma unroll
        for (int u = 0; u < 4; ++u) {
            float4 x = *reinterpret_cast<const float4*>(
                &W[(size_t)(k0 + row) * DD + n0 + c0 + u * 4]);
            Lt[row][c0 + u * 4 + 0] = x.x;
            Lt[row][c0 + u * 4 + 1] = x.y;
            Lt[row][c0 + u * 4 + 2] = x.z;
            Lt[row][c0 + u * 4 + 3] = x.w;
        }
    }
    __syncthreads();
    {
        int n  = t >> 2;                // n-local
        int kc = (t & 3) * 16;          // k-local chunk
        half8 h0, h1;
#pragma unroll
        for (int u = 0; u < 8; ++u) h0[u] = (f16)Lt[kc + u][n];
#pragma unroll
        for (int u = 0; u < 8; ++u) h1[u] = (f16)Lt[kc + 8 + u][n];
        f16* dst = &WT[(size_t)(n0 + n) * DD + k0 + kc];
        *reinterpret_cast<half8*>(dst) = h0;
        *reinterpret_cast<half8*>(dst + 8) = h1;
    }
}

// ============================================================
// Fused Q/K/V projection GEMM, f16 MFMA 16x16x32, 128x128 tile BK=64.
//   gz=0: Q = (query@Wq + bq)*0.125 -> f16 [bh][s][64]
//   gz=1: K                          -> f16 [bh][s][64]
//   gz=2: V^T = (value@Wv + bv)^T    -> f16 [bh][d][s]
// A,B both staged as [row][k] f16 rows (k contiguous, stride 1024).
// ============================================================
__global__ __launch_bounds__(256)
void proj3(const f16* __restrict__ Xq, const f16* __restrict__ Xk,
           const f16* __restrict__ Xv, const f16* __restrict__ WqT,
           const f16* __restrict__ WkT, const f16* __restrict__ WvT,
           const float* __restrict__ bq, const float* __restrict__ bk,
           const float* __restrict__ bv,
           f16* __restrict__ Qo, f16* __restrict__ Ko, f16* __restrict__ VTo)
{
    __shared__ f16 As[128 * 64];
    __shared__ f16 Bs[128 * 64];
    const int t = threadIdx.x, wid = t >> 6, l = t & 63, c = l & 15, g = l >> 4;
    const int gz = blockIdx.z;
    const f16 *Ap, *Bp; const float* bias; int m0, n0;
    if (gz == 2) { Ap = WvT; Bp = Xv; bias = bv; m0 = blockIdx.x * 128; n0 = blockIdx.y * 128; }
    else if (gz == 1) { Ap = Xk; Bp = WkT; bias = bk; m0 = blockIdx.y * 128; n0 = blockIdx.x * 128; }
    else { Ap = Xq; Bp = WqT; bias = bq; m0 = blockIdx.y * 128; n0 = blockIdx.x * 128; }
    const int wm = wid >> 1, wn = wid & 1;
    f32x4 acc[4][4] = {};
    char* AsB = (char*)As; char* BsB = (char*)Bs;

    for (int k0 = 0; k0 < DD; k0 += 64) {
        __syncthreads();
#pragma unroll
        for (int j = 0; j < 4; ++j) {
            int row = wid * 32 + j * 8 + (l >> 3);
            int slot = (l & 7) ^ (row & 7);
            gload16(Ap + (size_t)(m0 + row) * DD + k0 + slot * 8,
                    AsB + (wid * 32 + j * 8) * 128);
            gload16(Bp + (size_t)(n0 + row) * DD + k0 + slot * 8,
                    BsB + (wid * 32 + j * 8) * 128);
        }
        __syncthreads();
#pragma unroll
        for (int ks = 0; ks < 2; ++ks) {
            half8 af[4];
#pragma unroll
            for (int mt = 0; mt < 4; ++mt) {
                int row = wm * 64 + mt * 16 + c;
                af[mt] = *(const half8*)(AsB + row * 128 +
                         ((ks * 64 + g * 16) ^ ((row & 7) << 4)));
            }
#pragma unroll
            for (int nt = 0; nt < 4; ++nt) {
                int row = wn * 64 + nt * 16 + c;
                half8 bf = *(const half8*)(BsB + row * 128 +
                           ((ks * 64 + g * 16) ^ ((row & 7) << 4)));
#pragma unroll
                for (int mt = 0; mt < 4; ++mt)
                    acc[mt][nt] = __builtin_amdgcn_mfma_f32_16x16x32_f16(
                        af[mt], bf, acc[mt][nt], 0, 0, 0);
            }
        }
    }

    const float post = (gz == 0) ? 0.125f : 1.0f;
    if (gz < 2) {
        f16* dst = gz ? Ko : Qo;
#pragma unroll
        for (int nt = 0; nt < 4; ++nt) {
            int n = n0 + wn * 64 + nt * 16 + c;
            float bn = bias[n];
            int h = n >> 6, hd = n & 63;
#pragma unroll
            for (int mt = 0; mt < 4; ++mt)
#pragma unroll
                for (int reg = 0; reg < 4; ++reg) {
                    int m = m0 + wm * 64 + mt * 16 + 4 * g + reg;
                    int b = m >> 11, s = m & (SS - 1);
                    dst[(((size_t)(b * HH + h)) * SS + s) * 64 + hd] =
                        (f16)((acc[mt][nt][reg] + bn) * post);
                }
        }
    } else {
#pragma unroll
        for (int mt = 0; mt < 4; ++mt)
#pragma unroll
            for (int reg = 0; reg < 4; ++reg) {
                int m = m0 + wm * 64 + mt * 16 + 4 * g + reg;   // d index
                float bd = bias[m];
                int h = m >> 6, dl = m & 63;
#pragma unroll
                for (int nt = 0; nt < 4; ++nt) {
                    int n = n0 + wn * 64 + nt * 16 + c;          // s index
                    int b = n >> 11, s = n & (SS - 1);
                    VTo[(((size_t)(b * HH + h)) * 64 + dl) * SS + s] =
                        (f16)(acc[mt][nt][reg] + bd);
                }
            }
    }
}

// ============================================================
// Flash attention, f16 MFMA. Block = 128 q-rows of one (b,h); 4 waves x 32 rows.
// K-tiles of 64. Q pre-scaled 1/8. bias/mask fused into bm regs.
// LDS: Ks 8K (f16,[key][hd] swz), Vs 8K (f16,[d][key] swz), Ps 32K (f32 P, also
// initial Q staging region as f16).
// ============================================================
__global__ __launch_bounds__(256, 2)
void attn_fwd(const f16* __restrict__ Qw, const f16* __restrict__ Kw,
              const f16* __restrict__ VTw, const int* __restrict__ mask,
              const float* __restrict__ rpb, f16* __restrict__ AOh)
{
    __shared__ f16 Ks[64 * 64];
    __shared__ f16 Vs[64 * 64];
    __shared__ float Ps[128 * 64];
    char* KsB = (char*)Ks; char* VsB = (char*)Vs; char* PsB = (char*)Ps;

    const int t = threadIdx.x, wid = t >> 6, l = t & 63, c = l & 15, g = l >> 4;
    const int bh = blockIdx.x, b = bh >> 4, h = bh & 15;
    const int q0 = blockIdx.y * 128;
    const size_t baseSD = (size_t)bh * SS * 64;      // Q/K rows base
    const size_t baseDS = (size_t)bh * 64 * SS;      // V^T rows base

    // stage Q (128 rows x 64 f16) into Ps region, swizzled
#pragma unroll
    for (int j = 0; j < 4; ++j) {
        int row = wid * 32 + j * 8 + (l >> 3);
        int slot = (l & 7) ^ (row & 7);
        gload16(Qw + baseSD + (size_t)(q0 + row) * 64 + slot * 8,
                PsB + (wid * 32 + j * 8) * 128);
    }

    half8 qf[2][2];
    f32x4 acc_o[2][4] = {};
    float mrow[2][4], lrow[2][4];
#pragma unroll
    for (int mt = 0; mt < 2; ++mt)
#pragma unroll
        for (int r = 0; r < 4; ++r) { mrow[mt][r] = -INFINITY; lrow[mt][r] = 0.f; }

    for (int kt = 0; kt < SS / 64; ++kt) {
        const int j0 = kt * 64;
        __syncthreads();   // prior PV done (kt=0: Q staged)
        // stage K [key][hd] and V^T [d][key]
#pragma unroll
        for (int j = 0; j < 2; ++j) {
            int row = wid * 16 + j * 8 + (l >> 3);
            int slot = (l & 7) ^ (row & 7);
            gload16(Kw + baseSD + (size_t)(j0 + row) * 64 + slot * 8,
                    KsB + (wid * 16 + j * 8) * 128);
            gload16(VTw + baseDS + (size_t)row * SS + j0 + slot * 8,
                    VsB + (wid * 16 + j * 8) * 128);
        }
        // fused bias/mask prefetch: bm = mask ? bias : -1e9
        float bm[2][4][4];
#pragma unroll
        for (int mt = 0; mt < 2; ++mt)
#pragma unroll
            for (int reg = 0; reg < 4; ++reg) {
                int qrow = q0 + wid * 32 + mt * 16 + 4 * g + reg;
#pragma unroll
                for (int nt = 0; nt < 4; ++nt) {
                    int j = j0 + nt * 16 + c;
                    int mv = mask[((size_t)b * SS + qrow) * SS + j];
                    float bb = rpb[((size_t)j * SS + qrow) * HH + h];
                    bm[mt][nt][reg] = mv ? bb : -1e9f;
                }
            }
        __syncthreads();
        if (kt == 0) {
#pragma unroll
            for (int mt = 0; mt < 2; ++mt)
#pragma unroll
                for (int ks = 0; ks < 2; ++ks) {
                    int row = wid * 32 + mt * 16 + c;
                    qf[mt][ks] = *(const half8*)(PsB + row * 128 +
                                 ((ks * 64 + g * 16) ^ ((row & 7) << 4)));
                }
        }
        // QK^T
        f32x4 sc[2][4] = {};
#pragma unroll
        for (int ks = 0; ks < 2; ++ks)
#pragma unroll
            for (int nt = 0; nt < 4; ++nt) {
                int row = nt * 16 + c;
                half8 kf = *(const half8*)(KsB + row * 128 +
                           ((ks * 64 + g * 16) ^ ((row & 7) << 4)));
#pragma unroll
                for (int mt = 0; mt < 2; ++mt)
                    sc[mt][nt] = __builtin_amdgcn_mfma_f32_16x16x32_f16(
                        qf[mt][ks], kf, sc[mt][nt], 0, 0, 0);
            }
        // bias/mask + online softmax (rows live in (mt,reg), cols in (nt,c))
#pragma unroll
        for (int mt = 0; mt < 2; ++mt)
#pragma unroll
            for (int nt = 0; nt < 4; ++nt)
#pragma unroll
                for (int reg = 0; reg < 4; ++reg)
                    sc[mt][nt][reg] += bm[mt][nt][reg];
#pragma unroll
        for (int mt = 0; mt < 2; ++mt)
#pragma unroll
            for (int reg = 0; reg < 4; ++reg) {
                float s0 = sc[mt][0][reg], s1 = sc[mt][1][reg];
                float s2 = sc[mt][2][reg], s3 = sc[mt][3][reg];
                float rm = fmaxf(fmaxf(s0, s1), fmaxf(s2, s3));
                rm = fmaxf(rm, __shfl_xor(rm, 1));
                rm = fmaxf(rm, __shfl_xor(rm, 2));
                rm = fmaxf(rm, __shfl_xor(rm, 4));
                rm = fmaxf(rm, __shfl_xor(rm, 8));
                float mn = fmaxf(mrow[mt][reg], rm);
                float scal = __expf(mrow[mt][reg] - mn);
                mrow[mt][reg] = mn;
                float p0 = __expf(s0 - mn), p1 = __expf(s1 - mn);
                float p2 = __expf(s2 - mn), p3 = __expf(s3 - mn);
                sc[mt][0][reg] = p0; sc[mt][1][reg] = p1;
                sc[mt][2][reg] = p2; sc[mt][3][reg] = p3;
                float ps = p0 + p1 + p2 + p3;
                ps += __shfl_xor(ps, 1);
                ps += __shfl_xor(ps, 2);
                ps += __shfl_xor(ps, 4);
                ps += __shfl_xor(ps, 8);
                lrow[mt][reg] = lrow[mt][reg] * scal + ps;
#pragma unroll
                for (int nt = 0; nt < 4; ++nt) acc_o[mt][nt][reg] *= scal;
            }
        // write P (f32, swizzled) to Ps
#pragma unroll
        for (int mt = 0; mt < 2; ++mt)
#pragma unroll
            for (int reg = 0; reg < 4; ++reg) {
                int qrl = wid * 32 + mt * 16 + 4 * g + reg;
                char* pr = PsB + qrl * 256;
                int sw = (qrl & 7) << 4;
#pragma unroll
                for (int nt = 0; nt < 4; ++nt)
                    *(float*)(pr + ((nt * 64 + c * 4) ^ sw)) = sc[mt][nt][reg];
            }
        __syncthreads();
        // PV: acc_o += P @ V
#pragma unroll
        for (int ks = 0; ks < 2; ++ks) {
            half8 pa[2];
#pragma unroll
            for (int mt = 0; mt < 2; ++mt) {
                int row = wid * 32 + mt * 16 + c;
                char* base = PsB + row * 256;
                int sw = (row & 7) << 4;
                float4 x0 = *(const float4*)(base + ((ks * 128 + g * 32) ^ sw));
                float4 x1 = *(const float4*)(base + ((ks * 128 + g * 32 + 16) ^ sw));
                half8 v;
                v[0] = (f16)x0.x; v[1] = (f16)x0.y; v[2] = (f16)x0.z; v[3] = (f16)x0.w;
                v[4] = (f16)x1.x; v[5] = (f16)x1.y; v[6] = (f16)x1.z; v[7] = (f16)x1.w;
                pa[mt] = v;
            }
#pragma unroll
            for (int nt = 0; nt < 4; ++nt) {
                int row = nt * 16 + c;
                half8 vf = *(const half8*)(VsB + row * 128 +
                           ((ks * 64 + g * 16) ^ ((row & 7) << 4)));
#pragma unroll
                for (int mt = 0; mt < 2; ++mt)
                    acc_o[mt][nt] = __builtin_amdgcn_mfma_f32_16x16x32_f16(
                        pa[mt], vf, acc_o[mt][nt], 0, 0, 0);
            }
        }
    }
    // epilogue: normalize, store f16 AO in (b,s,1024) rows
#pragma unroll
    for (int mt = 0; mt < 2; ++mt)
#pragma unroll
        for (int reg = 0; reg < 4; ++reg) {
            int qrow = q0 + wid * 32 + mt * 16 + 4 * g + reg;
            float inv = 1.0f / lrow[mt][reg];
#pragma unroll
            for (int nt = 0; nt < 4; ++nt)
                AOh[((size_t)b * SS + qrow) * DD + h * 64 + nt * 16 + c] =
                    (f16)(acc_o[mt][nt][reg] * inv);
        }
}

// ============================================================
// Output projection: out(f32) = AO(f16) @ Wo + bo. Same tile scheme.
// ============================================================
__global__ __launch_bounds__(256)
void gemm_out(const f16* __restrict__ A, const f16* __restrict__ BT,
              const float* __restrict__ bias, float* __restrict__ out)
{
    __shared__ f16 As[128 * 64];
    __shared__ f16 Bs[128 * 64];
    const int t = threadIdx.x, wid = t >> 6, l = t & 63, c = l & 15, g = l >> 4;
    const int m0 = blockIdx.y * 128, n0 = blockIdx.x * 128;
    const int wm = wid >> 1, wn = wid & 1;
    f32x4 acc[4][4] = {};
    char* AsB = (char*)As; char* BsB = (char*)Bs;

    for (int k0 = 0; k0 < DD; k0 += 64) {
        __syncthreads();
#pragma unroll
        for (int j = 0; j < 4; ++j) {
            int row = wid * 32 + j * 8 + (l >> 3);
            int slot = (l & 7) ^ (row & 7);
            gload16(A + (size_t)(m0 + row) * DD + k0 + slot * 8,
                    AsB + (wid * 32 + j * 8) * 128);
            gload16(BT + (size_t)(n0 + row) * DD + k0 + slot * 8,
                    BsB + (wid * 32 + j * 8) * 128);
        }
        __syncthreads();
#pragma unroll
        for (int ks = 0; ks < 2; ++ks) {
            half8 af[4];
#pragma unroll
            for (int mt = 0; mt < 4; ++mt) {
                int row = wm * 64 + mt * 16 + c;
                af[mt] = *(const half8*)(AsB + row * 128 +
                         ((ks * 64 + g * 16) ^ ((row & 7) << 4)));
            }
#pragma unroll
            for (int nt = 0; nt < 4; ++nt) {
                int row = wn * 64 + nt * 16 + c;
                half8 bf = *(const half8*)(BsB + row * 128 +
                           ((ks * 64 + g * 16) ^ ((row & 7) << 4)));
#pragma unroll
                for (int mt = 0; mt < 4; ++mt)
                    acc[mt][nt] = __builtin_amdgcn_mfma_f32_16x16x32_f16(
                        af[mt], bf, acc[mt][nt], 0, 0, 0);
            }
        }
    }
#pragma unroll
    for (int nt = 0; nt < 4; ++nt) {
        int n = n0 + wn * 64 + nt * 16 + c;
        float bn = bias[n];
#pragma unroll
        for (int mt = 0; mt < 4; ++mt)
#pragma unroll
            for (int reg = 0; reg < 4; ++reg) {
                int m = m0 + wm * 64 + mt * 16 + 4 * g + reg;
                out[(size_t)m * DD + n] = acc[mt][nt][reg] + bn;
            }
    }
}

extern "C" void kernel_launch(void* const* d_in, const int* in_sizes, int n_in,
                              void* d_out, int out_size, void* d_ws, size_t ws_size,
                              hipStream_t stream)
{
    (void)in_sizes; (void)n_in; (void)out_size; (void)ws_size;

    const float* query = (const float*)d_in[0];
    const float* key   = (const float*)d_in[1];
    const float* value = (const float*)d_in[2];
    const int*   mask  = (const int*)d_in[3];
    const float* rpb   = (const float*)d_in[4];
    const float* Wq = (const float*)d_in[5];  const float* bq = (const float*)d_in[6];
    const float* Wk = (const float*)d_in[7];  const float* bk = (const float*)d_in[8];
    const float* Wv = (const float*)d_in[9];  const float* bv = (const float*)d_in[10];
    const float* Wo = (const float*)d_in[11]; const float* bo = (const float*)d_in[12];
    float* out = (float*)d_out;

    // workspace layout (f16 elements). AOh aliases Xq (dead after proj3).
    const size_t NX = (size_t)2 * SS * DD;   // 4096x1024
    const size_t NW = (size_t)DD * DD;       // 1024x1024
    f16* Xq  = (f16*)d_ws;
    f16* Xk  = Xq + NX;
    f16* Xv  = Xk + NX;
    f16* WqT = Xv + NX;
    f16* WkT = WqT + NW;
    f16* WvT = WkT + NW;
    f16* WoT = WvT + NW;
    f16* Qw  = WoT + NW;
    f16* Kw  = Qw + NX;
    f16* VTw = Kw + NX;
    f16* AOh = Xq;   // alias

    cvt_x<<<dim3(NX / 2048, 1, 3), 256, 0, stream>>>(query, key, value, Xq, Xk, Xv);
    cvt_wT<<<dim3(16, 16, 4), 256, 0, stream>>>(Wq, Wk, Wv, Wo, WqT, WkT, WvT, WoT);
    proj3<<<dim3(8, 32, 3), 256, 0, stream>>>(Xq, Xk, Xv, WqT, WkT, WvT,
                                              bq, bk, bv, Qw, Kw, VTw);
    attn_fwd<<<dim3(2 * HH, SS / 128), 256, 0, stream>>>(Qw, Kw, VTw, mask, rpb, AOh);
    gemm_out<<<dim3(8, 32), 256, 0, stream>>>(AOh, WoT, bo, out);
}

// Round 3
// 583.966 us; speedup vs baseline: 2.0923x; 1.2526x over previous
//
#include <hip/hip_runtime.h>
#include <math.h>

#define SS 2048
#define DD 1024
#define HH 16

typedef _Float16 f16;
typedef _Float16 half8 __attribute__((ext_vector_type(8)));
typedef float f32x4 __attribute__((ext_vector_type(4)));

#define LOG2E 1.44269504f

__device__ __forceinline__ void gload16(const void* g, void* lds) {
    __builtin_amdgcn_global_load_lds(
        (const __attribute__((address_space(1))) unsigned int*)g,
        (__attribute__((address_space(3))) unsigned int*)lds, 16, 0, 0);
}

// ============================================================
// prep 1: f32 -> f16 elementwise for query/key/value
// ============================================================
__global__ __launch_bounds__(256)
void cvt_x(const float* __restrict__ q, const float* __restrict__ k,
           const float* __restrict__ v, f16* __restrict__ oq,
           f16* __restrict__ ok, f16* __restrict__ ov)
{
    const int z = blockIdx.z;
    const float* src = z == 0 ? q : z == 1 ? k : v;
    f16* dst = z == 0 ? oq : z == 1 ? ok : ov;
    size_t i = ((size_t)blockIdx.x * 256 + threadIdx.x) * 8;
    float4 v0 = *reinterpret_cast<const float4*>(src + i);
    float4 v1 = *reinterpret_cast<const float4*>(src + i + 4);
    half8 h;
    h[0] = (f16)v0.x; h[1] = (f16)v0.y; h[2] = (f16)v0.z; h[3] = (f16)v0.w;
    h[4] = (f16)v1.x; h[5] = (f16)v1.y; h[6] = (f16)v1.z; h[7] = (f16)v1.w;
    *reinterpret_cast<half8*>(dst + i) = h;
}

// ============================================================
// prep 2: W (k,n) f32 -> WT (n,k) f16, 64x64 tiles through LDS
// ============================================================
__global__ __launch_bounds__(256)
void cvt_wT(const float* __restrict__ wq, const float* __restrict__ wk,
            const float* __restrict__ wv, const float* __restrict__ wo,
            f16* __restrict__ oq, f16* __restrict__ ok,
            f16* __restrict__ ov, f16* __restrict__ oo)
{
    __shared__ float Lt[64][65];
    const int z = blockIdx.z;
    const float* W = z == 0 ? wq : z == 1 ? wk : z == 2 ? wv : wo;
    f16* WT = z == 0 ? oq : z == 1 ? ok : z == 2 ? ov : oo;
    const int n0 = blockIdx.x * 64, k0 = blockIdx.y * 64;
    const int t = threadIdx.x;
    {
        int row = t >> 2;               // k-local
        int c0  = (t & 3) * 16;         // n-local
#pragma unroll
        for (int u = 0; u < 4; ++u) {
            float4 x = *reinterpret_cast<const float4*>(
                &W[(size_t)(k0 + row) * DD + n0 + c0 + u * 4]);
            Lt[row][c0 + u * 4 + 0] = x.x;
            Lt[row][c0 + u * 4 + 1] = x.y;
            Lt[row][c0 + u * 4 + 2] = x.z;
            Lt[row][c0 + u * 4 + 3] = x.w;
        }
    }
    __syncthreads();
    {
        int n  = t >> 2;                // n-local
        int kc = (t & 3) * 16;          // k-local chunk
        half8 h0, h1;
#pragma unroll
        for (int u = 0; u < 8; ++u) h0[u] = (f16)Lt[kc + u][n];
#pragma unroll
        for (int u = 0; u < 8; ++u) h1[u] = (f16)Lt[kc + 8 + u][n];
        f16* dst = &WT[(size_t)(n0 + n) * DD + k0 + kc];
        *reinterpret_cast<half8*>(dst) = h0;
        *reinterpret_cast<half8*>(dst + 8) = h1;
    }
}

// ============================================================
// prep 3: rpb[j][i][h] f32 -> rpbT[h][i][j] f16, scaled by log2(e).
// Reads coalesced along (i,h) (contiguous); each thread owns 4 output
// rows and writes 16-B chunks that L2 merges into full lines.
// grid (SS/64 i-tiles, SS/64 j-tiles), 256 threads.
// ============================================================
__global__ __launch_bounds__(256)
void cvt_rpbT(const float* __restrict__ rpb, f16* __restrict__ rpbT)
{
    const int t  = threadIdx.x;
    const int i0 = blockIdx.x * 64;
    const int j0 = blockIdx.y * 64;
    const int il = t >> 2;              // 0..63 (i-local)
    const int h0 = (t & 3) * 4;         // 0,4,8,12
    const float* src = rpb + ((size_t)j0 * SS + i0 + il) * HH + h0;
    f16* dst = rpbT + ((size_t)h0 * SS + (i0 + il)) * SS + j0;
    for (int jc = 0; jc < 8; ++jc) {
        half8 buf[4];
#pragma unroll
        for (int jj = 0; jj < 8; ++jj) {
            float4 v = *reinterpret_cast<const float4*>(
                src + (size_t)(jc * 8 + jj) * (SS * HH));
            buf[0][jj] = (f16)(v.x * LOG2E);
            buf[1][jj] = (f16)(v.y * LOG2E);
            buf[2][jj] = (f16)(v.z * LOG2E);
            buf[3][jj] = (f16)(v.w * LOG2E);
        }
#pragma unroll
        for (int k = 0; k < 4; ++k)
            *reinterpret_cast<half8*>(dst + (size_t)k * SS * SS + jc * 8) = buf[k];
    }
}

// ============================================================
// Fused Q/K/V projection GEMM, f16 MFMA 16x16x32, 128x128 tile BK=64.
//   gz=0: Q = (query@Wq + bq)*0.125*log2e -> f16 [bh][s][64]
//   gz=1: K                               -> f16 [bh][s][64]
//   gz=2: V^T = (value@Wv + bv)^T         -> f16 [bh][d][s]
// ============================================================
__global__ __launch_bounds__(256)
void proj3(const f16* __restrict__ Xq, const f16* __restrict__ Xk,
           const f16* __restrict__ Xv, const f16* __restrict__ WqT,
           const f16* __restrict__ WkT, const f16* __restrict__ WvT,
           const float* __restrict__ bq, const float* __restrict__ bk,
           const float* __restrict__ bv,
           f16* __restrict__ Qo, f16* __restrict__ Ko, f16* __restrict__ VTo)
{
    __shared__ f16 As[128 * 64];
    __shared__ f16 Bs[128 * 64];
    const int t = threadIdx.x, wid = t >> 6, l = t & 63, c = l & 15, g = l >> 4;
    const int gz = blockIdx.z;
    const f16 *Ap, *Bp; const float* bias; int m0, n0;
    if (gz == 2) { Ap = WvT; Bp = Xv; bias = bv; m0 = blockIdx.x * 128; n0 = blockIdx.y * 128; }
    else if (gz == 1) { Ap = Xk; Bp = WkT; bias = bk; m0 = blockIdx.y * 128; n0 = blockIdx.x * 128; }
    else { Ap = Xq; Bp = WqT; bias = bq; m0 = blockIdx.y * 128; n0 = blockIdx.x * 128; }
    const int wm = wid >> 1, wn = wid & 1;
    f32x4 acc[4][4] = {};
    char* AsB = (char*)As; char* BsB = (char*)Bs;

    for (int k0 = 0; k0 < DD; k0 += 64) {
        __syncthreads();
#pragma unroll
        for (int j = 0; j < 4; ++j) {
            int row = wid * 32 + j * 8 + (l >> 3);
            int slot = (l & 7) ^ (row & 7);
            gload16(Ap + (size_t)(m0 + row) * DD + k0 + slot * 8,
                    AsB + (wid * 32 + j * 8) * 128);
            gload16(Bp + (size_t)(n0 + row) * DD + k0 + slot * 8,
                    BsB + (wid * 32 + j * 8) * 128);
        }
        __syncthreads();
#pragma unroll
        for (int ks = 0; ks < 2; ++ks) {
            half8 af[4];
#pragma unroll
            for (int mt = 0; mt < 4; ++mt) {
                int row = wm * 64 + mt * 16 + c;
                af[mt] = *(const half8*)(AsB + row * 128 +
                         ((ks * 64 + g * 16) ^ ((row & 7) << 4)));
            }
#pragma unroll
            for (int nt = 0; nt < 4; ++nt) {
                int row = wn * 64 + nt * 16 + c;
                half8 bf = *(const half8*)(BsB + row * 128 +
                           ((ks * 64 + g * 16) ^ ((row & 7) << 4)));
#pragma unroll
                for (int mt = 0; mt < 4; ++mt)
                    acc[mt][nt] = __builtin_amdgcn_mfma_f32_16x16x32_f16(
                        af[mt], bf, acc[mt][nt], 0, 0, 0);
            }
        }
    }

    const float post = (gz == 0) ? 0.125f * LOG2E : 1.0f;
    if (gz < 2) {
        f16* dst = gz ? Ko : Qo;
#pragma unroll
        for (int nt = 0; nt < 4; ++nt) {
            int n = n0 + wn * 64 + nt * 16 + c;
            float bn = bias[n];
            int h = n >> 6, hd = n & 63;
#pragma unroll
            for (int mt = 0; mt < 4; ++mt)
#pragma unroll
                for (int reg = 0; reg < 4; ++reg) {
                    int m = m0 + wm * 64 + mt * 16 + 4 * g + reg;
                    int b = m >> 11, s = m & (SS - 1);
                    dst[(((size_t)(b * HH + h)) * SS + s) * 64 + hd] =
                        (f16)((acc[mt][nt][reg] + bn) * post);
                }
        }
    } else {
#pragma unroll
        for (int mt = 0; mt < 4; ++mt)
#pragma unroll
            for (int reg = 0; reg < 4; ++reg) {
                int m = m0 + wm * 64 + mt * 16 + 4 * g + reg;   // d index
                float bd = bias[m];
                int h = m >> 6, dl = m & 63;
#pragma unroll
                for (int nt = 0; nt < 4; ++nt) {
                    int n = n0 + wn * 64 + nt * 16 + c;          // s index
                    int b = n >> 11, s = n & (SS - 1);
                    VTo[(((size_t)(b * HH + h)) * 64 + dl) * SS + s] =
                        (f16)(acc[mt][nt][reg] + bd);
                }
            }
    }
}

// ============================================================
// Flash attention, f16 MFMA, base-2 softmax (Q and bias pre-scaled by
// log2e). Block = 64 q-rows of one (b,h); 4 waves x 16 rows. K-tiles 64.
// LDS: Qs 8K, Ks 8K, Vs 8K (all f16 swz), Ps 16K (f32 P). 40K -> 4 blk/CU.
// ============================================================
__global__ __launch_bounds__(256, 4)
void attn_fwd(const f16* __restrict__ Qw, const f16* __restrict__ Kw,
              const f16* __restrict__ VTw, const int* __restrict__ mask,
              const f16* __restrict__ rpbT, f16* __restrict__ AOh)
{
    __shared__ f16 Qs[64 * 64];
    __shared__ f16 Ks[64 * 64];
    __shared__ f16 Vs[64 * 64];
    __shared__ float Ps[64 * 64];
    char* QsB = (char*)Qs; char* KsB = (char*)Ks;
    char* VsB = (char*)Vs; char* PsB = (char*)Ps;

    const int t = threadIdx.x, wid = t >> 6, l = t & 63, c = l & 15, g = l >> 4;
    const int bh = blockIdx.x, b = bh >> 4, h = bh & 15;
    const int q0 = blockIdx.y * 64;
    const size_t baseSD = (size_t)bh * SS * 64;      // Q/K rows base
    const size_t baseDS = (size_t)bh * 64 * SS;      // V^T rows base
    const f16* rpbH = rpbT + (size_t)h * SS * SS;
    const int* maskB = mask + (size_t)b * SS * SS;

    // stage Q (64 rows x 64 f16), pre-swizzled source -> linear LDS
#pragma unroll
    for (int j = 0; j < 2; ++j) {
        int row = wid * 16 + j * 8 + (l >> 3);
        int slot = (l & 7) ^ (row & 7);
        gload16(Qw + baseSD + (size_t)(q0 + row) * 64 + slot * 8,
                QsB + (wid * 16 + j * 8) * 128);
    }

    half8 qf[2];
    f32x4 acc_o[4] = {};
    float mrow[4], lrow[4];
#pragma unroll
    for (int r = 0; r < 4; ++r) { mrow[r] = -INFINITY; lrow[r] = 0.f; }

    for (int kt = 0; kt < SS / 64; ++kt) {
        const int j0 = kt * 64;
        __syncthreads();   // prev PV done; kt=0: Q staged
        // stage K [key][hd] and V^T [d][key]
#pragma unroll
        for (int j = 0; j < 2; ++j) {
            int row = wid * 16 + j * 8 + (l >> 3);
            int slot = (l & 7) ^ (row & 7);
            gload16(Kw + baseSD + (size_t)(j0 + row) * 64 + slot * 8,
                    KsB + (wid * 16 + j * 8) * 128);
            gload16(VTw + baseDS + (size_t)row * SS + j0 + slot * 8,
                    VsB + (wid * 16 + j * 8) * 128);
        }
        if (kt == 0) {
#pragma unroll
            for (int ks = 0; ks < 2; ++ks) {
                int row = wid * 16 + c;
                qf[ks] = *(const half8*)(QsB + row * 128 +
                         ((ks * 64 + g * 16) ^ ((row & 7) << 4)));
            }
        }
        // fused bias/mask prefetch (coalesced): bm = mask ? bias*log2e : -1e9
        float bm[4][4];
#pragma unroll
        for (int reg = 0; reg < 4; ++reg) {
            int qrow = q0 + wid * 16 + 4 * g + reg;
            const f16* bp = rpbH + (size_t)qrow * SS + j0 + c;
            const int* mp = maskB + (size_t)qrow * SS + j0 + c;
#pragma unroll
            for (int nt = 0; nt < 4; ++nt) {
                float bb = (float)bp[nt * 16];
                int mv = mp[nt * 16];
                bm[reg][nt] = mv ? bb : -1e9f;
            }
        }
        __syncthreads();   // K/V staged
        // QK^T (scores already in log2 domain)
        f32x4 sc[4] = {};
#pragma unroll
        for (int ks = 0; ks < 2; ++ks)
#pragma unroll
            for (int nt = 0; nt < 4; ++nt) {
                int row = nt * 16 + c;
                half8 kf = *(const half8*)(KsB + row * 128 +
                           ((ks * 64 + g * 16) ^ ((row & 7) << 4)));
                sc[nt] = __builtin_amdgcn_mfma_f32_16x16x32_f16(
                    qf[ks], kf, sc[nt], 0, 0, 0);
            }
        // bias/mask + online softmax (base 2)
#pragma unroll
        for (int reg = 0; reg < 4; ++reg) {
            float s0 = sc[0][reg] + bm[reg][0];
            float s1 = sc[1][reg] + bm[reg][1];
            float s2 = sc[2][reg] + bm[reg][2];
            float s3 = sc[3][reg] + bm[reg][3];
            float rm = fmaxf(fmaxf(s0, s1), fmaxf(s2, s3));
            rm = fmaxf(rm, __shfl_xor(rm, 1));
            rm = fmaxf(rm, __shfl_xor(rm, 2));
            rm = fmaxf(rm, __shfl_xor(rm, 4));
            rm = fmaxf(rm, __shfl_xor(rm, 8));
            float mn = fmaxf(mrow[reg], rm);
            float scal = exp2f(mrow[reg] - mn);
            mrow[reg] = mn;
            float p0 = exp2f(s0 - mn), p1 = exp2f(s1 - mn);
            float p2 = exp2f(s2 - mn), p3 = exp2f(s3 - mn);
            sc[0][reg] = p0; sc[1][reg] = p1;
            sc[2][reg] = p2; sc[3][reg] = p3;
            float ps = p0 + p1 + p2 + p3;
            ps += __shfl_xor(ps, 1);
            ps += __shfl_xor(ps, 2);
            ps += __shfl_xor(ps, 4);
            ps += __shfl_xor(ps, 8);
            lrow[reg] = lrow[reg] * scal + ps;
#pragma unroll
            for (int nt = 0; nt < 4; ++nt) acc_o[nt][reg] *= scal;
        }
        // write P (f32, swizzled) to Ps
#pragma unroll
        for (int reg = 0; reg < 4; ++reg) {
            int qrl = wid * 16 + 4 * g + reg;
            char* pr = PsB + qrl * 256;
            int sw = (qrl & 7) << 4;
#pragma unroll
            for (int nt = 0; nt < 4; ++nt)
                *(float*)(pr + ((nt * 64 + c * 4) ^ sw)) = sc[nt][reg];
        }
        __syncthreads();
        // PV: acc_o += P @ V
#pragma unroll
        for (int ks = 0; ks < 2; ++ks) {
            half8 pa;
            {
                int row = wid * 16 + c;
                char* base = PsB + row * 256;
                int sw = (row & 7) << 4;
                float4 x0 = *(const float4*)(base + ((ks * 128 + g * 32) ^ sw));
                float4 x1 = *(const float4*)(base + ((ks * 128 + g * 32 + 16) ^ sw));
                pa[0] = (f16)x0.x; pa[1] = (f16)x0.y; pa[2] = (f16)x0.z; pa[3] = (f16)x0.w;
                pa[4] = (f16)x1.x; pa[5] = (f16)x1.y; pa[6] = (f16)x1.z; pa[7] = (f16)x1.w;
            }
#pragma unroll
            for (int nt = 0; nt < 4; ++nt) {
                int row = nt * 16 + c;
                half8 vf = *(const half8*)(VsB + row * 128 +
                           ((ks * 64 + g * 16) ^ ((row & 7) << 4)));
                acc_o[nt] = __builtin_amdgcn_mfma_f32_16x16x32_f16(
                    pa, vf, acc_o[nt], 0, 0, 0);
            }
        }
    }
    // epilogue: normalize, store f16 AO in (b,s,1024) rows
#pragma unroll
    for (int reg = 0; reg < 4; ++reg) {
        int qrow = q0 + wid * 16 + 4 * g + reg;
        float inv = 1.0f / lrow[reg];
#pragma unroll
        for (int nt = 0; nt < 4; ++nt)
            AOh[((size_t)b * SS + qrow) * DD + h * 64 + nt * 16 + c] =
                (f16)(acc_o[nt][reg] * inv);
    }
}

// ============================================================
// Output projection: out(f32) = AO(f16) @ Wo + bo.
// ============================================================
__global__ __launch_bounds__(256)
void gemm_out(const f16* __restrict__ A, const f16* __restrict__ BT,
              const float* __restrict__ bias, float* __restrict__ out)
{
    __shared__ f16 As[128 * 64];
    __shared__ f16 Bs[128 * 64];
    const int t = threadIdx.x, wid = t >> 6, l = t & 63, c = l & 15, g = l >> 4;
    const int m0 = blockIdx.y * 128, n0 = blockIdx.x * 128;
    const int wm = wid >> 1, wn = wid & 1;
    f32x4 acc[4][4] = {};
    char* AsB = (char*)As; char* BsB = (char*)Bs;

    for (int k0 = 0; k0 < DD; k0 += 64) {
        __syncthreads();
#pragma unroll
        for (int j = 0; j < 4; ++j) {
            int row = wid * 32 + j * 8 + (l >> 3);
            int slot = (l & 7) ^ (row & 7);
            gload16(A + (size_t)(m0 + row) * DD + k0 + slot * 8,
                    AsB + (wid * 32 + j * 8) * 128);
            gload16(BT + (size_t)(n0 + row) * DD + k0 + slot * 8,
                    BsB + (wid * 32 + j * 8) * 128);
        }
        __syncthreads();
#pragma unroll
        for (int ks = 0; ks < 2; ++ks) {
            half8 af[4];
#pragma unroll
            for (int mt = 0; mt < 4; ++mt) {
                int row = wm * 64 + mt * 16 + c;
                af[mt] = *(const half8*)(AsB + row * 128 +
                         ((ks * 64 + g * 16) ^ ((row & 7) << 4)));
            }
#pragma unroll
            for (int nt = 0; nt < 4; ++nt) {
                int row = wn * 64 + nt * 16 + c;
                half8 bf = *(const half8*)(BsB + row * 128 +
                           ((ks * 64 + g * 16) ^ ((row & 7) << 4)));
#pragma unroll
                for (int mt = 0; mt < 4; ++mt)
                    acc[mt][nt] = __builtin_amdgcn_mfma_f32_16x16x32_f16(
                        af[mt], bf, acc[mt][nt], 0, 0, 0);
            }
        }
    }
#pragma unroll
    for (int nt = 0; nt < 4; ++nt) {
        int n = n0 + wn * 64 + nt * 16 + c;
        float bn = bias[n];
#pragma unroll
        for (int mt = 0; mt < 4; ++mt)
#pragma unroll
            for (int reg = 0; reg < 4; ++reg) {
                int m = m0 + wm * 64 + mt * 16 + 4 * g + reg;
                out[(size_t)m * DD + n] = acc[mt][nt][reg] + bn;
            }
    }
}

extern "C" void kernel_launch(void* const* d_in, const int* in_sizes, int n_in,
                              void* d_out, int out_size, void* d_ws, size_t ws_size,
                              hipStream_t stream)
{
    (void)in_sizes; (void)n_in; (void)out_size; (void)ws_size;

    const float* query = (const float*)d_in[0];
    const float* key   = (const float*)d_in[1];
    const float* value = (const float*)d_in[2];
    const int*   mask  = (const int*)d_in[3];
    const float* rpb   = (const float*)d_in[4];
    const float* Wq = (const float*)d_in[5];  const float* bq = (const float*)d_in[6];
    const float* Wk = (const float*)d_in[7];  const float* bk = (const float*)d_in[8];
    const float* Wv = (const float*)d_in[9];  const float* bv = (const float*)d_in[10];
    const float* Wo = (const float*)d_in[11]; const float* bo = (const float*)d_in[12];
    float* out = (float*)d_out;

    // workspace layout (f16 elements). AOh aliases Xq (dead after proj3).
    const size_t NX = (size_t)2 * SS * DD;   // 4096x1024
    const size_t NW = (size_t)DD * DD;       // 1024x1024
    f16* Xq   = (f16*)d_ws;
    f16* Xk   = Xq + NX;
    f16* Xv   = Xk + NX;
    f16* WqT  = Xv + NX;
    f16* WkT  = WqT + NW;
    f16* WvT  = WkT + NW;
    f16* WoT  = WvT + NW;
    f16* Qw   = WoT + NW;
    f16* Kw   = Qw + NX;
    f16* VTw  = Kw + NX;
    f16* rpbT = VTw + NX;                    // 16*2048*2048 f16 = 128 MB
    f16* AOh  = Xq;   // alias

    cvt_x<<<dim3(NX / 2048, 1, 3), 256, 0, stream>>>(query, key, value, Xq, Xk, Xv);
    cvt_wT<<<dim3(16, 16, 4), 256, 0, stream>>>(Wq, Wk, Wv, Wo, WqT, WkT, WvT, WoT);
    cvt_rpbT<<<dim3(SS / 64, SS / 64), 256, 0, stream>>>(rpb, rpbT);
    proj3<<<dim3(8, 32, 3), 256, 0, stream>>>(Xq, Xk, Xv, WqT, WkT, WvT,
                                              bq, bk, bv, Qw, Kw, VTw);
    attn_fwd<<<dim3(2 * HH, SS / 64), 256, 0, stream>>>(Qw, Kw, VTw, mask, rpbT, AOh);
    gemm_out<<<dim3(8, 32), 256, 0, stream>>>(AOh, WoT, bo, out);
}